// Round 1
// baseline (2267.839 us; speedup 1.0000x reference)
//
#include <hip/hip_runtime.h>
#include <hip/hip_bf16.h>
#include <math.h>

#define DD 64
#define HIDC 128
#define FN 92
#define FE 41

__device__ __forceinline__ float sigmoidf_(float x){ return 1.f/(1.f+expf(-x)); }

// ---------------- pack/transpose small weights ----------------
__global__ void k_pack(const float* __restrict__ lin0_w, const float* __restrict__ nn1_w,
                       const float* __restrict__ root_w, const float* __restrict__ gwih,
                       const float* __restrict__ gwhh, const float* __restrict__ lwih,
                       const float* __restrict__ lwhh, const float* __restrict__ lin1_w,
                       float* __restrict__ lin0T, float* __restrict__ nn1T,
                       float* __restrict__ rootT, float* __restrict__ wihT,
                       float* __restrict__ whhT, float* __restrict__ lwihT,
                       float* __restrict__ lwhhT, float* __restrict__ lin1T)
{
  int idx = blockIdx.x*blockDim.x + threadIdx.x;
  if (idx < 92*64){ int k=idx/64, o=idx%64; lin0T[k*64+o] = lin0_w[o*92+k]; return; } idx -= 92*64;
  if (idx < 41*128){ int k=idx/128, h=idx%128; nn1T[k*128+h] = nn1_w[h*41+k]; return; } idx -= 41*128;
  if (idx < 64*64){ int i=idx/64, o=idx%64; rootT[i*64+o] = root_w[o*64+i]; return; } idx -= 64*64;
  if (idx < 64*192){ int i=idx/192, g=idx%192; wihT[i*192+g] = gwih[g*64+i]; return; } idx -= 64*192;
  if (idx < 64*192){ int i=idx/192, g=idx%192; whhT[i*192+g] = gwhh[g*64+i]; return; } idx -= 64*192;
  if (idx < 128*256){ int j=idx/256, t=idx%256; lwihT[j*256+t] = lwih[t*128+j]; return; } idx -= 128*256;
  if (idx < 64*256){ int j=idx/256, t=idx%256; lwhhT[j*256+t] = lwhh[t*64+j]; return; } idx -= 64*256;
  if (idx < 128*64){ int j=idx/64, t=idx%64; lin1T[j*64+t] = lin1_w[t*128+j]; return; }
}

// nn2_w [4096,128] -> nn2T [128,4096]
__global__ void k_t_nn2(const float* __restrict__ w, float* __restrict__ wt){
  __shared__ float t[32][33];
  int n0 = blockIdx.x*32, h0 = blockIdx.y*32;
  int tx = threadIdx.x, ty = threadIdx.y;
  t[ty][tx] = w[(size_t)(n0+ty)*128 + h0+tx];
  __syncthreads();
  wt[(size_t)(h0+ty)*4096 + n0+tx] = t[tx][ty];
}

// ---------------- node MLP: out = relu(x @ lin0_w^T + b) ----------------
__global__ __launch_bounds__(256) void k_node_mlp(const float* __restrict__ x,
    const float* __restrict__ lin0T, const float* __restrict__ lin0_b,
    float* __restrict__ out, int N)
{
  __shared__ float xs[4][FN];
  int base = blockIdx.x*4;
  for (int i=threadIdx.x; i<4*FN; i+=256){
    int n = base + i/FN;
    xs[i/FN][i%FN] = (n<N) ? x[(size_t)n*FN + i%FN] : 0.f;
  }
  __syncthreads();
  int ln = threadIdx.x>>6, o = threadIdx.x&63;
  int n = base+ln;
  if (n>=N) return;
  float acc = lin0_b[o];
  #pragma unroll 4
  for (int k=0;k<FN;k++) acc = fmaf(xs[ln][k], lin0T[k*64+o], acc);
  out[(size_t)n*64+o] = fmaxf(acc, 0.f);
}

// ---------------- edge MLP: hidden = relu(edge_attr @ nn1_w^T + b) ----------------
__global__ __launch_bounds__(256) void k_edge_mlp(const float* __restrict__ ea,
    const float* __restrict__ nn1T, const float* __restrict__ nn1_b,
    float* __restrict__ hidden, int E)
{
  __shared__ float es[2][FE];
  int base = blockIdx.x*2;
  for (int i=threadIdx.x; i<2*FE; i+=256){
    int e = base + i/FE;
    es[i/FE][i%FE] = (e<E) ? ea[(size_t)e*FE + i%FE] : 0.f;
  }
  __syncthreads();
  int le = threadIdx.x>>7, h = threadIdx.x&127;
  int e = base+le;
  if (e>=E) return;
  float acc = nn1_b[h];
  #pragma unroll
  for (int k=0;k<FE;k++) acc = fmaf(es[le][k], nn1T[k*128+h], acc);
  hidden[(size_t)e*128+h] = fmaxf(acc, 0.f);
}

// ---------------- degree count ----------------
__global__ void k_count(const int* __restrict__ dst, float* __restrict__ deg, int E){
  int e = blockIdx.x*blockDim.x + threadIdx.x;
  if (e < E) atomicAdd(&deg[dst[e]], 1.f);
}

// ---------------- We GEMM: C[M,4096] = A[M,128] @ Bt[128,4096] + bias ----------------
__global__ __launch_bounds__(256) void k_gemm_we(const float* __restrict__ A,
    const float* __restrict__ Bt, const float* __restrict__ bias,
    float* __restrict__ C, int M)
{
  __shared__ float As[32][68];
  __shared__ float Bs[32][68];
  const int tid = threadIdx.x;
  const int bm = blockIdx.y*64, bn = blockIdx.x*64;
  const int row = tid>>4, col = tid&15;
  const int ra = tid>>2;          // 0..63
  const int ka = (tid&3)*8;       // 0,8,16,24
  const int kb = tid>>3;          // 0..31
  const int nb = (tid&7)*8;       // 0..56
  const int arow = min(bm+ra, M-1);
  float acc[4][4] = {{0.f}};
  for (int k0 = 0; k0 < 128; k0 += 32){
    float4 a0 = *(const float4*)(A + (size_t)arow*128 + k0+ka);
    float4 a1 = *(const float4*)(A + (size_t)arow*128 + k0+ka+4);
    As[ka+0][ra]=a0.x; As[ka+1][ra]=a0.y; As[ka+2][ra]=a0.z; As[ka+3][ra]=a0.w;
    As[ka+4][ra]=a1.x; As[ka+5][ra]=a1.y; As[ka+6][ra]=a1.z; As[ka+7][ra]=a1.w;
    float4 b0 = *(const float4*)(Bt + (size_t)(k0+kb)*4096 + bn+nb);
    float4 b1 = *(const float4*)(Bt + (size_t)(k0+kb)*4096 + bn+nb+4);
    *(float4*)&Bs[kb][nb] = b0;
    *(float4*)&Bs[kb][nb+4] = b1;
    __syncthreads();
    #pragma unroll
    for (int k=0;k<32;k++){
      float4 av = *(const float4*)&As[k][row*4];
      float4 bv = *(const float4*)&Bs[k][col*4];
      acc[0][0]=fmaf(av.x,bv.x,acc[0][0]); acc[0][1]=fmaf(av.x,bv.y,acc[0][1]);
      acc[0][2]=fmaf(av.x,bv.z,acc[0][2]); acc[0][3]=fmaf(av.x,bv.w,acc[0][3]);
      acc[1][0]=fmaf(av.y,bv.x,acc[1][0]); acc[1][1]=fmaf(av.y,bv.y,acc[1][1]);
      acc[1][2]=fmaf(av.y,bv.z,acc[1][2]); acc[1][3]=fmaf(av.y,bv.w,acc[1][3]);
      acc[2][0]=fmaf(av.z,bv.x,acc[2][0]); acc[2][1]=fmaf(av.z,bv.y,acc[2][1]);
      acc[2][2]=fmaf(av.z,bv.z,acc[2][2]); acc[2][3]=fmaf(av.z,bv.w,acc[2][3]);
      acc[3][0]=fmaf(av.w,bv.x,acc[3][0]); acc[3][1]=fmaf(av.w,bv.y,acc[3][1]);
      acc[3][2]=fmaf(av.w,bv.z,acc[3][2]); acc[3][3]=fmaf(av.w,bv.w,acc[3][3]);
    }
    __syncthreads();
  }
  const int n = bn + col*4;
  float4 bs4 = *(const float4*)(bias + n);
  #pragma unroll
  for (int i=0;i<4;i++){
    int m = bm + row*4 + i;
    if (m < M){
      float4 o;
      o.x = acc[i][0]+bs4.x; o.y = acc[i][1]+bs4.y;
      o.z = acc[i][2]+bs4.z; o.w = acc[i][3]+bs4.w;
      *(float4*)(C + (size_t)m*4096 + n) = o;
    }
  }
}

// ---------------- msg + scatter: one wave per edge ----------------
__global__ __launch_bounds__(256) void k_msg(const float* __restrict__ We,
    const float* __restrict__ out, const int* __restrict__ src,
    const int* __restrict__ dst, float* __restrict__ agg, int e0, int cnt)
{
  int w = (int)((blockIdx.x*256u + threadIdx.x)>>6);
  int lane = threadIdx.x&63;
  if (w >= cnt) return;
  int e = e0 + w;
  int s = src[e];
  float v = out[(size_t)s*64 + lane];
  const float* W = We + (size_t)w*4096;
  float acc = 0.f;
  #pragma unroll
  for (int i=0;i<64;i++){
    acc = fmaf(__shfl(v, i, 64), W[i*64+lane], acc);
  }
  atomicAdd(&agg[(size_t)dst[e]*64 + lane], acc);
}

// ---------------- agg-normalize + root + GRU (fused) ----------------
__global__ __launch_bounds__(256) void k_node_update(const float* __restrict__ outOld,
    const float* __restrict__ agg, const float* __restrict__ deg,
    const float* __restrict__ rootT, const float* __restrict__ conv_b,
    const float* __restrict__ wihT, const float* __restrict__ whhT,
    const float* __restrict__ b_ih, const float* __restrict__ b_hh,
    float* __restrict__ outNew, int N)
{
  __shared__ float hs[4][64];
  __shared__ float ms[4][64];
  int ln = threadIdx.x>>6, o = threadIdx.x&63;
  int n = blockIdx.x*4+ln;
  bool ok = (n<N);
  float h = ok ? outOld[(size_t)n*64+o] : 0.f;
  hs[ln][o] = h;
  __syncthreads();
  float root = 0.f;
  #pragma unroll 8
  for (int i=0;i<64;i++) root = fmaf(hs[ln][i], rootT[i*64+o], root);
  float d = ok ? fmaxf(deg[n], 1.f) : 1.f;
  float a = ok ? agg[(size_t)n*64+o]/d : 0.f;
  float m = fmaxf(a + root + conv_b[o], 0.f);
  ms[ln][o] = m;
  __syncthreads();
  float gir=b_ih[o], giz=b_ih[64+o], gin=b_ih[128+o];
  float ghr=b_hh[o], ghz=b_hh[64+o], ghn=b_hh[128+o];
  #pragma unroll 4
  for (int i=0;i<64;i++){
    float mi = ms[ln][i], hi = hs[ln][i];
    gir = fmaf(mi, wihT[i*192+o],      gir);
    giz = fmaf(mi, wihT[i*192+64+o],   giz);
    gin = fmaf(mi, wihT[i*192+128+o],  gin);
    ghr = fmaf(hi, whhT[i*192+o],      ghr);
    ghz = fmaf(hi, whhT[i*192+64+o],   ghz);
    ghn = fmaf(hi, whhT[i*192+128+o],  ghn);
  }
  float r = sigmoidf_(gir+ghr);
  float z = sigmoidf_(giz+ghz);
  float nn = tanhf(gin + r*ghn);
  if (ok) outNew[(size_t)n*64+o] = (1.f-z)*nn + z*h;
}

// ---------------- Set2Set (3 steps) + final MLP: one block per graph ----------------
__global__ __launch_bounds__(256) void k_set2set(const float* __restrict__ out,
    const int* __restrict__ batch, int N,
    const float* __restrict__ lwihT, const float* __restrict__ lwhhT,
    const float* __restrict__ b_ih, const float* __restrict__ b_hh,
    const float* __restrict__ lin1T, const float* __restrict__ lin1_b,
    const float* __restrict__ lin2_w, const float* __restrict__ lin2_b,
    float* __restrict__ y)
{
  __shared__ float qstar[128], hl[64], cl[64], g[256];
  __shared__ float rpart[4][64], spart[4], redm[4], zs[64];
  __shared__ int sb[2];
  const int tid = threadIdx.x;
  const int b = blockIdx.x;
  const int wid = tid>>6, lane = tid&63;
  if (tid < 128) qstar[tid] = 0.f;
  if (tid < 64){ hl[tid]=0.f; cl[tid]=0.f; }
  if (tid == 0){
    int lo=0, hi=N;
    while (lo<hi){ int mid=(lo+hi)>>1; if (batch[mid] < b) lo=mid+1; else hi=mid; }
    sb[0]=lo;
    int lo2=lo, hi2=N;
    while (lo2<hi2){ int mid=(lo2+hi2)>>1; if (batch[mid] < b+1) lo2=mid+1; else hi2=mid; }
    sb[1]=lo2;
  }
  __syncthreads();
  const int nlo = sb[0], nhi = sb[1];
  for (int step=0; step<3; step++){
    float gs = b_ih[tid] + b_hh[tid];
    for (int j=0;j<128;j++) gs = fmaf(qstar[j], lwihT[j*256+tid], gs);
    for (int j=0;j<64;j++)  gs = fmaf(hl[j],    lwhhT[j*256+tid], gs);
    g[tid] = gs;
    __syncthreads();
    if (tid < 64){
      float ig = sigmoidf_(g[tid]);
      float fg = sigmoidf_(g[64+tid]);
      float gg = tanhf(g[128+tid]);
      float og = sigmoidf_(g[192+tid]);
      float c = fg*cl[tid] + ig*gg;
      cl[tid] = c;
      hl[tid] = og*tanhf(c);
    }
    __syncthreads();
    float qv = hl[lane];
    // pass 1: segment max of e
    float lm = -INFINITY;
    for (int n = nlo + wid; n < nhi; n += 4){
      float p = out[(size_t)n*64 + lane]*qv;
      p += __shfl_xor(p,1); p += __shfl_xor(p,2); p += __shfl_xor(p,4);
      p += __shfl_xor(p,8); p += __shfl_xor(p,16); p += __shfl_xor(p,32);
      lm = fmaxf(lm, p);
    }
    if (lane==0) redm[wid] = lm;
    __syncthreads();
    if (tid==0) redm[0] = fmaxf(fmaxf(redm[0],redm[1]), fmaxf(redm[2],redm[3]));
    __syncthreads();
    float gmax = redm[0];
    // pass 2: sum exp and weighted sum
    float sw = 0.f, racc = 0.f;
    for (int n = nlo + wid; n < nhi; n += 4){
      float ol = out[(size_t)n*64 + lane];
      float p = ol*qv;
      p += __shfl_xor(p,1); p += __shfl_xor(p,2); p += __shfl_xor(p,4);
      p += __shfl_xor(p,8); p += __shfl_xor(p,16); p += __shfl_xor(p,32);
      float a = expf(p - gmax);
      sw += a;
      racc = fmaf(a, ol, racc);
    }
    rpart[wid][lane] = racc;
    if (lane==0) spart[wid] = sw;
    __syncthreads();
    if (tid < 64){
      float r = rpart[0][tid]+rpart[1][tid]+rpart[2][tid]+rpart[3][tid];
      float s = spart[0]+spart[1]+spart[2]+spart[3];
      qstar[tid] = hl[tid];
      qstar[64+tid] = (nhi>nlo) ? r/s : 0.f;
    }
    __syncthreads();
  }
  if (tid < 64){
    float acc = lin1_b[tid];
    for (int j=0;j<128;j++) acc = fmaf(qstar[j], lin1T[j*64+tid], acc);
    zs[tid] = fmaxf(acc, 0.f);
  }
  __syncthreads();
  if (tid < 64){
    float v = zs[lane]*lin2_w[lane];
    v += __shfl_xor(v,1); v += __shfl_xor(v,2); v += __shfl_xor(v,4);
    v += __shfl_xor(v,8); v += __shfl_xor(v,16); v += __shfl_xor(v,32);
    if (lane==0) y[b] = v + lin2_b[0];
  }
}

extern "C" void kernel_launch(void* const* d_in, const int* in_sizes, int n_in,
                              void* d_out, int out_size, void* d_ws, size_t ws_size,
                              hipStream_t stream)
{
  const float* x      = (const float*)d_in[0];
  const float* eattr  = (const float*)d_in[1];
  const float* lin0_w = (const float*)d_in[2];
  const float* lin0_b = (const float*)d_in[3];
  const float* nn1_w  = (const float*)d_in[4];
  const float* nn1_b  = (const float*)d_in[5];
  const float* nn2_w  = (const float*)d_in[6];
  const float* nn2_b  = (const float*)d_in[7];
  const float* root_w = (const float*)d_in[8];
  const float* conv_b = (const float*)d_in[9];
  const float* gwih   = (const float*)d_in[10];
  const float* gwhh   = (const float*)d_in[11];
  const float* gbih   = (const float*)d_in[12];
  const float* gbhh   = (const float*)d_in[13];
  const float* lwih   = (const float*)d_in[14];
  const float* lwhh   = (const float*)d_in[15];
  const float* lbih   = (const float*)d_in[16];
  const float* lbhh   = (const float*)d_in[17];
  const float* lin1_w = (const float*)d_in[18];
  const float* lin1_b = (const float*)d_in[19];
  const float* lin2_w = (const float*)d_in[20];
  const float* lin2_b = (const float*)d_in[21];
  const int*   eidx   = (const int*)d_in[22];
  const int*   batch  = (const int*)d_in[23];

  const int N = in_sizes[0]/FN;
  const int E = in_sizes[1]/FE;
  const int* srcI = eidx;
  const int* dstI = eidx + E;

  char* w = (char*)d_ws;
  size_t off = 0;
  auto alloc = [&](size_t bytes)->char* {
    char* p = w + off;
    off = (off + bytes + 255) & ~(size_t)255;
    return p;
  };
  float* degw  = (float*)alloc((size_t)N*4);
  float* outA  = (float*)alloc((size_t)N*64*4);
  float* outB  = (float*)alloc((size_t)N*64*4);
  float* agg   = (float*)alloc((size_t)N*64*4);
  float* hidden= (float*)alloc((size_t)E*128*4);
  float* nn2T  = (float*)alloc((size_t)128*4096*4);
  float* lin0T = (float*)alloc((size_t)92*64*4);
  float* nn1T  = (float*)alloc((size_t)41*128*4);
  float* rootT = (float*)alloc((size_t)64*64*4);
  float* wihT  = (float*)alloc((size_t)64*192*4);
  float* whhT  = (float*)alloc((size_t)64*192*4);
  float* lwihT = (float*)alloc((size_t)128*256*4);
  float* lwhhT = (float*)alloc((size_t)64*256*4);
  float* lin1T = (float*)alloc((size_t)128*64*4);

  size_t avail = (ws_size > off) ? (ws_size - off) : 0;
  long long capLL = (long long)(avail / ((size_t)4096*4));
  int cap = (capLL > (long long)E) ? E : (int)capLL;
  cap &= ~63;
  if (cap <= 0) cap = 64;            // assume ws is at least moderately sized
  float* webuf = (float*)alloc((size_t)cap*4096*4);
  const bool full = (cap >= E);

  hipMemsetAsync(degw, 0, (size_t)N*4, stream);
  k_pack<<<(97152+255)/256, 256, 0, stream>>>(lin0_w, nn1_w, root_w, gwih, gwhh,
      lwih, lwhh, lin1_w, lin0T, nn1T, rootT, wihT, whhT, lwihT, lwhhT, lin1T);
  k_t_nn2<<<dim3(128,4), dim3(32,32), 0, stream>>>(nn2_w, nn2T);
  k_node_mlp<<<(N+3)/4, 256, 0, stream>>>(x, lin0T, lin0_b, outA, N);
  k_edge_mlp<<<(E+1)/2, 256, 0, stream>>>(eattr, nn1T, nn1_b, hidden, E);
  k_count<<<(E+255)/256, 256, 0, stream>>>(dstI, degw, E);
  if (full){
    k_gemm_we<<<dim3(64, E/64), 256, 0, stream>>>(hidden, nn2T, nn2_b, webuf, E);
  }

  float* cur = outA; float* nxt = outB;
  for (int conv=0; conv<2; conv++){
    hipMemsetAsync(agg, 0, (size_t)N*64*4, stream);
    if (full){
      k_msg<<<(E+3)/4, 256, 0, stream>>>(webuf, cur, srcI, dstI, agg, 0, E);
    } else {
      for (int e0=0; e0<E; e0+=cap){
        int m = (E-e0 < cap) ? (E-e0) : cap;
        k_gemm_we<<<dim3(64,(m+63)/64), 256, 0, stream>>>(hidden + (size_t)e0*128, nn2T, nn2_b, webuf, m);
        k_msg<<<(m+3)/4, 256, 0, stream>>>(webuf, cur, srcI, dstI, agg, e0, m);
      }
    }
    k_node_update<<<(N+3)/4, 256, 0, stream>>>(cur, agg, degw, rootT, conv_b,
        wihT, whhT, gbih, gbhh, nxt, N);
    float* t = cur; cur = nxt; nxt = t;
  }

  k_set2set<<<128, 256, 0, stream>>>(cur, batch, N, lwihT, lwhhT, lbih, lbhh,
      lin1T, lin1_b, lin2_w, lin2_b, (float*)d_out);
}

// Round 2
// 1234.987 us; speedup vs baseline: 1.8363x; 1.8363x over previous
//
#include <hip/hip_runtime.h>
#include <hip/hip_bf16.h>
#include <math.h>

#define DD 64
#define HIDC 128
#define FN 92
#define FE 41

__device__ __forceinline__ float sigmoidf_(float x){ return 1.f/(1.f+expf(-x)); }

// ---------------- pack/transpose small weights ----------------
__global__ void k_pack(const float* __restrict__ lin0_w, const float* __restrict__ nn1_w,
                       const float* __restrict__ root_w, const float* __restrict__ gwih,
                       const float* __restrict__ gwhh, const float* __restrict__ lwih,
                       const float* __restrict__ lwhh, const float* __restrict__ lin1_w,
                       float* __restrict__ lin0T, float* __restrict__ nn1T,
                       float* __restrict__ rootT, float* __restrict__ wihT,
                       float* __restrict__ whhT, float* __restrict__ lwihT,
                       float* __restrict__ lwhhT, float* __restrict__ lin1T)
{
  int idx = blockIdx.x*blockDim.x + threadIdx.x;
  if (idx < 92*64){ int k=idx/64, o=idx%64; lin0T[k*64+o] = lin0_w[o*92+k]; return; } idx -= 92*64;
  if (idx < 41*128){ int k=idx/128, h=idx%128; nn1T[k*128+h] = nn1_w[h*41+k]; return; } idx -= 41*128;
  if (idx < 64*64){ int i=idx/64, o=idx%64; rootT[i*64+o] = root_w[o*64+i]; return; } idx -= 64*64;
  if (idx < 64*192){ int i=idx/192, g=idx%192; wihT[i*192+g] = gwih[g*64+i]; return; } idx -= 64*192;
  if (idx < 64*192){ int i=idx/192, g=idx%192; whhT[i*192+g] = gwhh[g*64+i]; return; } idx -= 64*192;
  if (idx < 128*256){ int j=idx/256, t=idx%256; lwihT[j*256+t] = lwih[t*128+j]; return; } idx -= 128*256;
  if (idx < 64*256){ int j=idx/256, t=idx%256; lwhhT[j*256+t] = lwhh[t*64+j]; return; } idx -= 64*256;
  if (idx < 128*64){ int j=idx/64, t=idx%64; lin1T[j*64+t] = lin1_w[t*128+j]; return; }
}

// Repack nn2_w [4096,128] into B2[chunk][i][o*64+h]: B2[idx] with
// idx = c*262144 + i*4096 + o*64 + h  <-  nn2_w[(i*64+o)*128 + c*64 + h]
__global__ void k_pack_b2(const float* __restrict__ nn2_w, float* __restrict__ B2){
  int idx = blockIdx.x*256 + threadIdx.x;
  if (idx >= 524288) return;
  int c = idx >> 18;
  int r = idx & 262143;
  int i = r >> 12;
  int oh = r & 4095;
  int o = oh >> 6, h = oh & 63;
  B2[idx] = nn2_w[(size_t)(i*64+o)*128 + c*64 + h];
}

// ---------------- node MLP: out = relu(x @ lin0_w^T + b) ----------------
__global__ __launch_bounds__(256) void k_node_mlp(const float* __restrict__ x,
    const float* __restrict__ lin0T, const float* __restrict__ lin0_b,
    float* __restrict__ out, int N)
{
  __shared__ float xs[4][FN];
  int base = blockIdx.x*4;
  for (int i=threadIdx.x; i<4*FN; i+=256){
    int n = base + i/FN;
    xs[i/FN][i%FN] = (n<N) ? x[(size_t)n*FN + i%FN] : 0.f;
  }
  __syncthreads();
  int ln = threadIdx.x>>6, o = threadIdx.x&63;
  int n = base+ln;
  if (n>=N) return;
  float acc = lin0_b[o];
  #pragma unroll 4
  for (int k=0;k<FN;k++) acc = fmaf(xs[ln][k], lin0T[k*64+o], acc);
  out[(size_t)n*64+o] = fmaxf(acc, 0.f);
}

// ---------------- edge MLP: hidden = relu(edge_attr @ nn1_w^T + b) ----------------
__global__ __launch_bounds__(256) void k_edge_mlp(const float* __restrict__ ea,
    const float* __restrict__ nn1T, const float* __restrict__ nn1_b,
    float* __restrict__ hidden, int E)
{
  __shared__ float es[2][FE];
  int base = blockIdx.x*2;
  for (int i=threadIdx.x; i<2*FE; i+=256){
    int e = base + i/FE;
    es[i/FE][i%FE] = (e<E) ? ea[(size_t)e*FE + i%FE] : 0.f;
  }
  __syncthreads();
  int le = threadIdx.x>>7, h = threadIdx.x&127;
  int e = base+le;
  if (e>=E) return;
  float acc = nn1_b[h];
  #pragma unroll
  for (int k=0;k<FE;k++) acc = fmaf(es[le][k], nn1T[k*128+h], acc);
  hidden[(size_t)e*128+h] = fmaxf(acc, 0.f);
}

// ---------------- degree count ----------------
__global__ void k_count(const int* __restrict__ dst, float* __restrict__ deg, int E){
  int e = blockIdx.x*blockDim.x + threadIdx.x;
  if (e < E) atomicAdd(&deg[dst[e]], 1.f);
}

// ---------------- Q GEMM: Q[M,4096] = A[M,64] @ B[64,4096] ----------------
// A row stride 64; B row stride 4096. Output Q[n][c'] with c' = o*64+h.
__global__ __launch_bounds__(256) void k_qgemm(const float* __restrict__ A,
    const float* __restrict__ B, float* __restrict__ C, int M)
{
  __shared__ float As[32][68];
  __shared__ float Bs[32][68];
  const int tid = threadIdx.x;
  const int bm = blockIdx.y*64, bn = blockIdx.x*64;
  const int row = tid>>4, col = tid&15;
  const int ra = tid>>2;          // 0..63
  const int ka = (tid&3)*8;       // 0,8,16,24
  const int kb = tid>>3;          // 0..31
  const int nb = (tid&7)*8;       // 0..56
  const int arow = min(bm+ra, M-1);
  float acc[4][4] = {{0.f}};
  for (int k0 = 0; k0 < 64; k0 += 32){
    float4 a0 = *(const float4*)(A + (size_t)arow*64 + k0+ka);
    float4 a1 = *(const float4*)(A + (size_t)arow*64 + k0+ka+4);
    As[ka+0][ra]=a0.x; As[ka+1][ra]=a0.y; As[ka+2][ra]=a0.z; As[ka+3][ra]=a0.w;
    As[ka+4][ra]=a1.x; As[ka+5][ra]=a1.y; As[ka+6][ra]=a1.z; As[ka+7][ra]=a1.w;
    float4 b0 = *(const float4*)(B + (size_t)(k0+kb)*4096 + bn+nb);
    float4 b1 = *(const float4*)(B + (size_t)(k0+kb)*4096 + bn+nb+4);
    *(float4*)&Bs[kb][nb] = b0;
    *(float4*)&Bs[kb][nb+4] = b1;
    __syncthreads();
    #pragma unroll
    for (int k=0;k<32;k++){
      float4 av = *(const float4*)&As[k][row*4];
      float4 bv = *(const float4*)&Bs[k][col*4];
      acc[0][0]=fmaf(av.x,bv.x,acc[0][0]); acc[0][1]=fmaf(av.x,bv.y,acc[0][1]);
      acc[0][2]=fmaf(av.x,bv.z,acc[0][2]); acc[0][3]=fmaf(av.x,bv.w,acc[0][3]);
      acc[1][0]=fmaf(av.y,bv.x,acc[1][0]); acc[1][1]=fmaf(av.y,bv.y,acc[1][1]);
      acc[1][2]=fmaf(av.y,bv.z,acc[1][2]); acc[1][3]=fmaf(av.y,bv.w,acc[1][3]);
      acc[2][0]=fmaf(av.z,bv.x,acc[2][0]); acc[2][1]=fmaf(av.z,bv.y,acc[2][1]);
      acc[2][2]=fmaf(av.z,bv.z,acc[2][2]); acc[2][3]=fmaf(av.z,bv.w,acc[2][3]);
      acc[3][0]=fmaf(av.w,bv.x,acc[3][0]); acc[3][1]=fmaf(av.w,bv.y,acc[3][1]);
      acc[3][2]=fmaf(av.w,bv.z,acc[3][2]); acc[3][3]=fmaf(av.w,bv.w,acc[3][3]);
    }
    __syncthreads();
  }
  const int n = bn + col*4;
  #pragma unroll
  for (int i=0;i<4;i++){
    int m = bm + row*4 + i;
    if (m < M){
      float4 o;
      o.x = acc[i][0]; o.y = acc[i][1]; o.z = acc[i][2]; o.w = acc[i][3];
      *(float4*)(C + (size_t)m*4096 + n) = o;
    }
  }
}

// ---------------- bias term: bterm[n,o] = sum_i out[n,i]*nn2_b[i*64+o] ----------------
__global__ __launch_bounds__(256) void k_bterm(const float* __restrict__ out,
    const float* __restrict__ nn2_b, float* __restrict__ bterm, int N)
{
  __shared__ float hs[4][64];
  int ln = threadIdx.x>>6, o = threadIdx.x&63;
  int n = blockIdx.x*4+ln;
  hs[ln][o] = (n<N) ? out[(size_t)n*64+o] : 0.f;
  __syncthreads();
  if (n>=N) return;
  float acc = 0.f;
  #pragma unroll 8
  for (int i=0;i<64;i++) acc = fmaf(hs[ln][i], nn2_b[i*64+o], acc);
  bterm[(size_t)n*64+o] = acc;
}

// ---------------- edge gather: msg[e,o] (+)= sum_h hidden[e,h0+h]*Q[src][o*64+h] ------
// PASS 0: msg = bterm[src] + partial;  PASS 1: val = msg + partial, atomic scatter to agg
template<int PASS>
__global__ __launch_bounds__(256) void k_edge_gather(const float* __restrict__ Q,
    const float* __restrict__ hidden, int h0,
    const float* __restrict__ bterm, const int* __restrict__ src,
    const int* __restrict__ dst, float* __restrict__ msg,
    float* __restrict__ agg, int E)
{
  int e = (int)((blockIdx.x*256u + threadIdx.x)>>6);
  int lane = threadIdx.x&63;
  if (e >= E) return;
  int s = src[e];
  float hv = hidden[(size_t)e*128 + h0 + lane];
  const float4* qp = (const float4*)(Q + (size_t)s*4096 + (size_t)lane*64);
  float acc = 0.f;
  #pragma unroll
  for (int j=0;j<16;j++){
    float4 q = qp[j];
    acc = fmaf(__shfl(hv, 4*j+0, 64), q.x, acc);
    acc = fmaf(__shfl(hv, 4*j+1, 64), q.y, acc);
    acc = fmaf(__shfl(hv, 4*j+2, 64), q.z, acc);
    acc = fmaf(__shfl(hv, 4*j+3, 64), q.w, acc);
  }
  if (PASS == 0){
    msg[(size_t)e*64 + lane] = bterm[(size_t)s*64 + lane] + acc;
  } else {
    float v = msg[(size_t)e*64 + lane] + acc;
    atomicAdd(&agg[(size_t)dst[e]*64 + lane], v);
  }
}

// ---------------- agg-normalize + root + GRU (fused) ----------------
__global__ __launch_bounds__(256) void k_node_update(const float* __restrict__ outOld,
    const float* __restrict__ agg, const float* __restrict__ deg,
    const float* __restrict__ rootT, const float* __restrict__ conv_b,
    const float* __restrict__ wihT, const float* __restrict__ whhT,
    const float* __restrict__ b_ih, const float* __restrict__ b_hh,
    float* __restrict__ outNew, int N)
{
  __shared__ float hs[4][64];
  __shared__ float ms[4][64];
  int ln = threadIdx.x>>6, o = threadIdx.x&63;
  int n = blockIdx.x*4+ln;
  bool ok = (n<N);
  float h = ok ? outOld[(size_t)n*64+o] : 0.f;
  hs[ln][o] = h;
  __syncthreads();
  float root = 0.f;
  #pragma unroll 8
  for (int i=0;i<64;i++) root = fmaf(hs[ln][i], rootT[i*64+o], root);
  float d = ok ? fmaxf(deg[n], 1.f) : 1.f;
  float a = ok ? agg[(size_t)n*64+o]/d : 0.f;
  float m = fmaxf(a + root + conv_b[o], 0.f);
  ms[ln][o] = m;
  __syncthreads();
  float gir=b_ih[o], giz=b_ih[64+o], gin=b_ih[128+o];
  float ghr=b_hh[o], ghz=b_hh[64+o], ghn=b_hh[128+o];
  #pragma unroll 4
  for (int i=0;i<64;i++){
    float mi = ms[ln][i], hi = hs[ln][i];
    gir = fmaf(mi, wihT[i*192+o],      gir);
    giz = fmaf(mi, wihT[i*192+64+o],   giz);
    gin = fmaf(mi, wihT[i*192+128+o],  gin);
    ghr = fmaf(hi, whhT[i*192+o],      ghr);
    ghz = fmaf(hi, whhT[i*192+64+o],   ghz);
    ghn = fmaf(hi, whhT[i*192+128+o],  ghn);
  }
  float r = sigmoidf_(gir+ghr);
  float z = sigmoidf_(giz+ghz);
  float nn = tanhf(gin + r*ghn);
  if (ok) outNew[(size_t)n*64+o] = (1.f-z)*nn + z*h;
}

// ---------------- Set2Set (3 steps) + final MLP: one block per graph ----------------
__global__ __launch_bounds__(256) void k_set2set(const float* __restrict__ out,
    const int* __restrict__ batch, int N,
    const float* __restrict__ lwihT, const float* __restrict__ lwhhT,
    const float* __restrict__ b_ih, const float* __restrict__ b_hh,
    const float* __restrict__ lin1T, const float* __restrict__ lin1_b,
    const float* __restrict__ lin2_w, const float* __restrict__ lin2_b,
    float* __restrict__ y)
{
  __shared__ float qstar[128], hl[64], cl[64], g[256];
  __shared__ float rpart[4][64], spart[4], redm[4], zs[64];
  __shared__ int sb[2];
  const int tid = threadIdx.x;
  const int b = blockIdx.x;
  const int wid = tid>>6, lane = tid&63;
  if (tid < 128) qstar[tid] = 0.f;
  if (tid < 64){ hl[tid]=0.f; cl[tid]=0.f; }
  if (tid == 0){
    int lo=0, hi=N;
    while (lo<hi){ int mid=(lo+hi)>>1; if (batch[mid] < b) lo=mid+1; else hi=mid; }
    sb[0]=lo;
    int lo2=lo, hi2=N;
    while (lo2<hi2){ int mid=(lo2+hi2)>>1; if (batch[mid] < b+1) lo2=mid+1; else hi2=mid; }
    sb[1]=lo2;
  }
  __syncthreads();
  const int nlo = sb[0], nhi = sb[1];
  for (int step=0; step<3; step++){
    float gs = b_ih[tid] + b_hh[tid];
    for (int j=0;j<128;j++) gs = fmaf(qstar[j], lwihT[j*256+tid], gs);
    for (int j=0;j<64;j++)  gs = fmaf(hl[j],    lwhhT[j*256+tid], gs);
    g[tid] = gs;
    __syncthreads();
    if (tid < 64){
      float ig = sigmoidf_(g[tid]);
      float fg = sigmoidf_(g[64+tid]);
      float gg = tanhf(g[128+tid]);
      float og = sigmoidf_(g[192+tid]);
      float c = fg*cl[tid] + ig*gg;
      cl[tid] = c;
      hl[tid] = og*tanhf(c);
    }
    __syncthreads();
    float qv = hl[lane];
    float lm = -INFINITY;
    for (int n = nlo + wid; n < nhi; n += 4){
      float p = out[(size_t)n*64 + lane]*qv;
      p += __shfl_xor(p,1); p += __shfl_xor(p,2); p += __shfl_xor(p,4);
      p += __shfl_xor(p,8); p += __shfl_xor(p,16); p += __shfl_xor(p,32);
      lm = fmaxf(lm, p);
    }
    if (lane==0) redm[wid] = lm;
    __syncthreads();
    if (tid==0) redm[0] = fmaxf(fmaxf(redm[0],redm[1]), fmaxf(redm[2],redm[3]));
    __syncthreads();
    float gmax = redm[0];
    float sw = 0.f, racc = 0.f;
    for (int n = nlo + wid; n < nhi; n += 4){
      float ol = out[(size_t)n*64 + lane];
      float p = ol*qv;
      p += __shfl_xor(p,1); p += __shfl_xor(p,2); p += __shfl_xor(p,4);
      p += __shfl_xor(p,8); p += __shfl_xor(p,16); p += __shfl_xor(p,32);
      float a = expf(p - gmax);
      sw += a;
      racc = fmaf(a, ol, racc);
    }
    rpart[wid][lane] = racc;
    if (lane==0) spart[wid] = sw;
    __syncthreads();
    if (tid < 64){
      float r = rpart[0][tid]+rpart[1][tid]+rpart[2][tid]+rpart[3][tid];
      float s = spart[0]+spart[1]+spart[2]+spart[3];
      qstar[tid] = hl[tid];
      qstar[64+tid] = (nhi>nlo) ? r/s : 0.f;
    }
    __syncthreads();
  }
  if (tid < 64){
    float acc = lin1_b[tid];
    for (int j=0;j<128;j++) acc = fmaf(qstar[j], lin1T[j*64+tid], acc);
    zs[tid] = fmaxf(acc, 0.f);
  }
  __syncthreads();
  if (tid < 64){
    float v = zs[lane]*lin2_w[lane];
    v += __shfl_xor(v,1); v += __shfl_xor(v,2); v += __shfl_xor(v,4);
    v += __shfl_xor(v,8); v += __shfl_xor(v,16); v += __shfl_xor(v,32);
    if (lane==0) y[b] = v + lin2_b[0];
  }
}

extern "C" void kernel_launch(void* const* d_in, const int* in_sizes, int n_in,
                              void* d_out, int out_size, void* d_ws, size_t ws_size,
                              hipStream_t stream)
{
  const float* x      = (const float*)d_in[0];
  const float* eattr  = (const float*)d_in[1];
  const float* lin0_w = (const float*)d_in[2];
  const float* lin0_b = (const float*)d_in[3];
  const float* nn1_w  = (const float*)d_in[4];
  const float* nn1_b  = (const float*)d_in[5];
  const float* nn2_w  = (const float*)d_in[6];
  const float* nn2_b  = (const float*)d_in[7];
  const float* root_w = (const float*)d_in[8];
  const float* conv_b = (const float*)d_in[9];
  const float* gwih   = (const float*)d_in[10];
  const float* gwhh   = (const float*)d_in[11];
  const float* gbih   = (const float*)d_in[12];
  const float* gbhh   = (const float*)d_in[13];
  const float* lwih   = (const float*)d_in[14];
  const float* lwhh   = (const float*)d_in[15];
  const float* lbih   = (const float*)d_in[16];
  const float* lbhh   = (const float*)d_in[17];
  const float* lin1_w = (const float*)d_in[18];
  const float* lin1_b = (const float*)d_in[19];
  const float* lin2_w = (const float*)d_in[20];
  const float* lin2_b = (const float*)d_in[21];
  const int*   eidx   = (const int*)d_in[22];
  const int*   batch  = (const int*)d_in[23];

  const int N = in_sizes[0]/FN;
  const int E = in_sizes[1]/FE;
  const int* srcI = eidx;
  const int* dstI = eidx + E;

  char* w = (char*)d_ws;
  size_t off = 0;
  auto alloc = [&](size_t bytes)->char* {
    char* p = w + off;
    off = (off + bytes + 255) & ~(size_t)255;
    return p;
  };
  float* degw  = (float*)alloc((size_t)N*4);
  float* outA  = (float*)alloc((size_t)N*64*4);
  float* outB  = (float*)alloc((size_t)N*64*4);
  float* agg   = (float*)alloc((size_t)N*64*4);
  float* bterm = (float*)alloc((size_t)N*64*4);
  float* hidden= (float*)alloc((size_t)E*128*4);
  float* msg   = (float*)alloc((size_t)E*64*4);
  float* B2    = (float*)alloc((size_t)524288*4);
  float* lin0T = (float*)alloc((size_t)92*64*4);
  float* nn1T  = (float*)alloc((size_t)41*128*4);
  float* rootT = (float*)alloc((size_t)64*64*4);
  float* wihT  = (float*)alloc((size_t)64*192*4);
  float* whhT  = (float*)alloc((size_t)64*192*4);
  float* lwihT = (float*)alloc((size_t)128*256*4);
  float* lwhhT = (float*)alloc((size_t)64*256*4);
  float* lin1T = (float*)alloc((size_t)128*64*4);
  float* Q     = (float*)alloc((size_t)N*4096*4);   // one h-chunk: [n][o*64+h]

  hipMemsetAsync(degw, 0, (size_t)N*4, stream);
  k_pack<<<(97152+255)/256, 256, 0, stream>>>(lin0_w, nn1_w, root_w, gwih, gwhh,
      lwih, lwhh, lin1_w, lin0T, nn1T, rootT, wihT, whhT, lwihT, lwhhT, lin1T);
  k_pack_b2<<<524288/256, 256, 0, stream>>>(nn2_w, B2);
  k_node_mlp<<<(N+3)/4, 256, 0, stream>>>(x, lin0T, lin0_b, outA, N);
  k_edge_mlp<<<(E+1)/2, 256, 0, stream>>>(eattr, nn1T, nn1_b, hidden, E);
  k_count<<<(E+255)/256, 256, 0, stream>>>(dstI, degw, E);

  float* cur = outA; float* nxt = outB;
  const int gemmGy = (N+63)/64;
  for (int conv=0; conv<2; conv++){
    k_bterm<<<(N+3)/4, 256, 0, stream>>>(cur, nn2_b, bterm, N);
    hipMemsetAsync(agg, 0, (size_t)N*64*4, stream);
    // chunk 0 (h in [0,64))
    k_qgemm<<<dim3(64, gemmGy), 256, 0, stream>>>(cur, B2, Q, N);
    k_edge_gather<0><<<(E+3)/4, 256, 0, stream>>>(Q, hidden, 0, bterm, srcI, dstI, msg, agg, E);
    // chunk 1 (h in [64,128))
    k_qgemm<<<dim3(64, gemmGy), 256, 0, stream>>>(cur, B2 + 262144, Q, N);
    k_edge_gather<1><<<(E+3)/4, 256, 0, stream>>>(Q, hidden, 64, bterm, srcI, dstI, msg, agg, E);
    k_node_update<<<(N+3)/4, 256, 0, stream>>>(cur, agg, degw, rootT, conv_b,
        wihT, whhT, gbih, gbhh, nxt, N);
    float* t = cur; cur = nxt; nxt = t;
  }

  k_set2set<<<128, 256, 0, stream>>>(cur, batch, N, lwihT, lwhhT, lbih, lbhh,
      lin1T, lin1_b, lin2_w, lin2_b, (float*)d_out);
}

// Round 3
// 852.490 us; speedup vs baseline: 2.6603x; 1.4487x over previous
//
#include <hip/hip_runtime.h>
#include <hip/hip_bf16.h>
#include <math.h>

#define DD 64
#define HIDC 128
#define FN 92
#define FE 41

__device__ __forceinline__ float sigmoidf_(float x){ return 1.f/(1.f+expf(-x)); }

// ---------------- pack/transpose small weights ----------------
__global__ void k_pack(const float* __restrict__ lin0_w, const float* __restrict__ nn1_w,
                       const float* __restrict__ root_w, const float* __restrict__ gwih,
                       const float* __restrict__ gwhh, const float* __restrict__ lwih,
                       const float* __restrict__ lwhh, const float* __restrict__ lin1_w,
                       float* __restrict__ lin0T, float* __restrict__ nn1T,
                       float* __restrict__ rootT, float* __restrict__ wihT,
                       float* __restrict__ whhT, float* __restrict__ lwihT,
                       float* __restrict__ lwhhT, float* __restrict__ lin1T)
{
  int idx = blockIdx.x*blockDim.x + threadIdx.x;
  if (idx < 92*64){ int k=idx/64, o=idx%64; lin0T[k*64+o] = lin0_w[o*92+k]; return; } idx -= 92*64;
  if (idx < 41*128){ int k=idx/128, h=idx%128; nn1T[k*128+h] = nn1_w[h*41+k]; return; } idx -= 41*128;
  if (idx < 64*64){ int i=idx/64, o=idx%64; rootT[i*64+o] = root_w[o*64+i]; return; } idx -= 64*64;
  if (idx < 64*192){ int i=idx/192, g=idx%192; wihT[i*192+g] = gwih[g*64+i]; return; } idx -= 64*192;
  if (idx < 64*192){ int i=idx/192, g=idx%192; whhT[i*192+g] = gwhh[g*64+i]; return; } idx -= 64*192;
  if (idx < 128*256){ int j=idx/256, t=idx%256; lwihT[j*256+t] = lwih[t*128+j]; return; } idx -= 128*256;
  if (idx < 64*256){ int j=idx/256, t=idx%256; lwhhT[j*256+t] = lwhh[t*64+j]; return; } idx -= 64*256;
  if (idx < 128*64){ int j=idx/64, t=idx%64; lin1T[j*64+t] = lin1_w[t*128+j]; return; }
}

// Repack nn2_w [4096,128] into B2[c][i][h*64+o]:
// B2[c*262144 + i*4096 + h*64 + o] = nn2_w[(i*64+o)*128 + c*64 + h]
__global__ void k_pack_b2(const float* __restrict__ nn2_w, float* __restrict__ B2){
  int idx = blockIdx.x*256 + threadIdx.x;
  if (idx >= 524288) return;
  int c = idx >> 18;
  int r = idx & 262143;
  int i = r >> 12;
  int ho = r & 4095;
  int h = ho >> 6, o = ho & 63;
  B2[idx] = nn2_w[(size_t)(i*64+o)*128 + c*64 + h];
}

// ---------------- node MLP: out = relu(x @ lin0_w^T + b) ----------------
__global__ __launch_bounds__(256) void k_node_mlp(const float* __restrict__ x,
    const float* __restrict__ lin0T, const float* __restrict__ lin0_b,
    float* __restrict__ out, int N)
{
  __shared__ float xs[4][FN];
  int base = blockIdx.x*4;
  for (int i=threadIdx.x; i<4*FN; i+=256){
    int n = base + i/FN;
    xs[i/FN][i%FN] = (n<N) ? x[(size_t)n*FN + i%FN] : 0.f;
  }
  __syncthreads();
  int ln = threadIdx.x>>6, o = threadIdx.x&63;
  int n = base+ln;
  if (n>=N) return;
  float acc = lin0_b[o];
  #pragma unroll 4
  for (int k=0;k<FN;k++) acc = fmaf(xs[ln][k], lin0T[k*64+o], acc);
  out[(size_t)n*64+o] = fmaxf(acc, 0.f);
}

// ---------------- edge MLP: hidden = relu(edge_attr @ nn1_w^T + b) ----------------
__global__ __launch_bounds__(256) void k_edge_mlp(const float* __restrict__ ea,
    const float* __restrict__ nn1T, const float* __restrict__ nn1_b,
    float* __restrict__ hidden, int E)
{
  __shared__ float es[2][FE];
  int base = blockIdx.x*2;
  for (int i=threadIdx.x; i<2*FE; i+=256){
    int e = base + i/FE;
    es[i/FE][i%FE] = (e<E) ? ea[(size_t)e*FE + i%FE] : 0.f;
  }
  __syncthreads();
  int le = threadIdx.x>>7, h = threadIdx.x&127;
  int e = base+le;
  if (e>=E) return;
  float acc = nn1_b[h];
  #pragma unroll
  for (int k=0;k<FE;k++) acc = fmaf(es[le][k], nn1T[k*128+h], acc);
  hidden[(size_t)e*128+h] = fmaxf(acc, 0.f);
}

// ---------------- degree + src histogram ----------------
__global__ void k_count(const int* __restrict__ dst, const int* __restrict__ src,
                        float* __restrict__ deg, int* __restrict__ scnt, int E){
  int e = blockIdx.x*blockDim.x + threadIdx.x;
  if (e < E){
    atomicAdd(&deg[dst[e]], 1.f);
    atomicAdd(&scnt[src[e]], 1);
  }
}

// ---------------- 3-kernel exclusive scan over scnt[N] ----------------
__global__ void k_scan1(const int* __restrict__ cnt, int* __restrict__ excl,
                        int* __restrict__ bsum, int N){
  __shared__ int buf[256];
  int i = blockIdx.x*256 + threadIdx.x;
  int v = (i<N) ? cnt[i] : 0;
  buf[threadIdx.x] = v;
  __syncthreads();
  #pragma unroll
  for (int off=1; off<256; off<<=1){
    int t = (threadIdx.x>=off) ? buf[threadIdx.x-off] : 0;
    __syncthreads();
    buf[threadIdx.x] += t;
    __syncthreads();
  }
  if (i<N) excl[i] = buf[threadIdx.x] - v;
  if (threadIdx.x==255) bsum[blockIdx.x] = buf[255];
}
__global__ void k_scan2(int* __restrict__ bsum, int nb){
  __shared__ int buf[256];
  int v = (threadIdx.x<nb) ? bsum[threadIdx.x] : 0;
  buf[threadIdx.x] = v;
  __syncthreads();
  #pragma unroll
  for (int off=1; off<256; off<<=1){
    int t = (threadIdx.x>=off) ? buf[threadIdx.x-off] : 0;
    __syncthreads();
    buf[threadIdx.x] += t;
    __syncthreads();
  }
  if (threadIdx.x<nb) bsum[threadIdx.x] = buf[threadIdx.x] - v;
}
__global__ void k_scan3(int* __restrict__ starts, int* __restrict__ cursor,
                        const int* __restrict__ bsum, int N, int E){
  int i = blockIdx.x*256 + threadIdx.x;
  if (i<N){
    int s = starts[i] + bsum[blockIdx.x];
    starts[i] = s;
    cursor[i] = s;
  }
  if (i==0) starts[N] = E;
}

// ---------------- scatter: sortedE grouped by src ----------------
__global__ void k_sort(const int* __restrict__ src, int* __restrict__ cursor,
                       int* __restrict__ sortedE, int E){
  int e = blockIdx.x*256 + threadIdx.x;
  if (e < E){
    int p = atomicAdd(&cursor[src[e]], 1);
    sortedE[p] = e;
  }
}

// ---------------- Q GEMM: Q[M,4096] = A[M,64] @ B[64,4096] ----------------
__global__ __launch_bounds__(256) void k_qgemm(const float* __restrict__ A,
    const float* __restrict__ B, float* __restrict__ C, int M)
{
  __shared__ float As[32][68];
  __shared__ float Bs[32][68];
  const int tid = threadIdx.x;
  const int bm = blockIdx.y*64, bn = blockIdx.x*64;
  const int row = tid>>4, col = tid&15;
  const int ra = tid>>2;          // 0..63
  const int ka = (tid&3)*8;       // 0,8,16,24
  const int kb = tid>>3;          // 0..31
  const int nb = (tid&7)*8;       // 0..56
  const int arow = min(bm+ra, M-1);
  float acc[4][4] = {{0.f}};
  for (int k0 = 0; k0 < 64; k0 += 32){
    float4 a0 = *(const float4*)(A + (size_t)arow*64 + k0+ka);
    float4 a1 = *(const float4*)(A + (size_t)arow*64 + k0+ka+4);
    As[ka+0][ra]=a0.x; As[ka+1][ra]=a0.y; As[ka+2][ra]=a0.z; As[ka+3][ra]=a0.w;
    As[ka+4][ra]=a1.x; As[ka+5][ra]=a1.y; As[ka+6][ra]=a1.z; As[ka+7][ra]=a1.w;
    float4 b0 = *(const float4*)(B + (size_t)(k0+kb)*4096 + bn+nb);
    float4 b1 = *(const float4*)(B + (size_t)(k0+kb)*4096 + bn+nb+4);
    *(float4*)&Bs[kb][nb] = b0;
    *(float4*)&Bs[kb][nb+4] = b1;
    __syncthreads();
    #pragma unroll
    for (int k=0;k<32;k++){
      float4 av = *(const float4*)&As[k][row*4];
      float4 bv = *(const float4*)&Bs[k][col*4];
      acc[0][0]=fmaf(av.x,bv.x,acc[0][0]); acc[0][1]=fmaf(av.x,bv.y,acc[0][1]);
      acc[0][2]=fmaf(av.x,bv.z,acc[0][2]); acc[0][3]=fmaf(av.x,bv.w,acc[0][3]);
      acc[1][0]=fmaf(av.y,bv.x,acc[1][0]); acc[1][1]=fmaf(av.y,bv.y,acc[1][1]);
      acc[1][2]=fmaf(av.y,bv.z,acc[1][2]); acc[1][3]=fmaf(av.y,bv.w,acc[1][3]);
      acc[2][0]=fmaf(av.z,bv.x,acc[2][0]); acc[2][1]=fmaf(av.z,bv.y,acc[2][1]);
      acc[2][2]=fmaf(av.z,bv.z,acc[2][2]); acc[2][3]=fmaf(av.z,bv.w,acc[2][3]);
      acc[3][0]=fmaf(av.w,bv.x,acc[3][0]); acc[3][1]=fmaf(av.w,bv.y,acc[3][1]);
      acc[3][2]=fmaf(av.w,bv.z,acc[3][2]); acc[3][3]=fmaf(av.w,bv.w,acc[3][3]);
    }
    __syncthreads();
  }
  const int n = bn + col*4;
  #pragma unroll
  for (int i=0;i<4;i++){
    int m = bm + row*4 + i;
    if (m < M){
      float4 o;
      o.x = acc[i][0]; o.y = acc[i][1]; o.z = acc[i][2]; o.w = acc[i][3];
      *(float4*)(C + (size_t)m*4096 + n) = o;
    }
  }
}

// ---------------- bias term: bterm[n,o] = sum_i out[n,i]*nn2_b[i*64+o] ----------------
__global__ __launch_bounds__(256) void k_bterm(const float* __restrict__ out,
    const float* __restrict__ nn2_b, float* __restrict__ bterm, int N)
{
  __shared__ float hs[4][64];
  int ln = threadIdx.x>>6, o = threadIdx.x&63;
  int n = blockIdx.x*4+ln;
  hs[ln][o] = (n<N) ? out[(size_t)n*64+o] : 0.f;
  __syncthreads();
  if (n>=N) return;
  float acc = 0.f;
  #pragma unroll 8
  for (int i=0;i<64;i++) acc = fmaf(hs[ln][i], nn2_b[i*64+o], acc);
  bterm[(size_t)n*64+o] = acc;
}

// ---------------- edge gather (src-sorted, coalesced Q[h*64+o] reads) ----------------
// one wave per edge (sorted order); lane = sg*16+oq covers o=oq*4..+3, h==sg (mod 4)
// PASS 0: msg = bterm[src] + partial;  PASS 1: atomicAdd(agg[dst], msg + partial)
template<int PASS>
__global__ __launch_bounds__(256) void k_edge_gather(const float* __restrict__ Q,
    const float* __restrict__ hidden, int h0,
    const float* __restrict__ bterm, const int* __restrict__ src,
    const int* __restrict__ dst, const int* __restrict__ sortedE,
    float* __restrict__ msg, float* __restrict__ agg, int E)
{
  __shared__ float hs[4][64];
  __shared__ float red[4][64];
  const int wv = threadIdx.x>>6, lane = threadIdx.x&63;
  const int ew = blockIdx.x*4 + wv;
  const bool valid = (ew < E);
  const int e = valid ? sortedE[ew] : sortedE[0];
  const int s = src[e];
  hs[wv][lane] = hidden[(size_t)e*128 + h0 + lane];
  __syncthreads();
  const int sg = lane>>4, oq = lane&15;
  const float* qrow = Q + (size_t)s*4096 + sg*64 + oq*4;
  float a0=0.f, a1=0.f, a2=0.f, a3=0.f;
  #pragma unroll
  for (int j=0;j<16;j++){
    float4 q = *(const float4*)(qrow + j*256);
    float hv = hs[wv][j*4 + sg];
    a0 = fmaf(hv, q.x, a0); a1 = fmaf(hv, q.y, a1);
    a2 = fmaf(hv, q.z, a2); a3 = fmaf(hv, q.w, a3);
  }
  a0 += __shfl_xor(a0,16); a0 += __shfl_xor(a0,32);
  a1 += __shfl_xor(a1,16); a1 += __shfl_xor(a1,32);
  a2 += __shfl_xor(a2,16); a2 += __shfl_xor(a2,32);
  a3 += __shfl_xor(a3,16); a3 += __shfl_xor(a3,32);
  if (lane < 16){
    float4 v4; v4.x=a0; v4.y=a1; v4.z=a2; v4.w=a3;
    *(float4*)&red[wv][lane*4] = v4;
  }
  __syncthreads();
  if (valid){
    float rv = red[wv][lane];
    if (PASS == 0){
      msg[(size_t)e*64 + lane] = bterm[(size_t)s*64 + lane] + rv;
    } else {
      atomicAdd(&agg[(size_t)dst[e]*64 + lane], msg[(size_t)e*64 + lane] + rv);
    }
  }
}

// ---------------- agg-normalize + root + GRU (fused) ----------------
__global__ __launch_bounds__(256) void k_node_update(const float* __restrict__ outOld,
    const float* __restrict__ agg, const float* __restrict__ deg,
    const float* __restrict__ rootT, const float* __restrict__ conv_b,
    const float* __restrict__ wihT, const float* __restrict__ whhT,
    const float* __restrict__ b_ih, const float* __restrict__ b_hh,
    float* __restrict__ outNew, int N)
{
  __shared__ float hs[4][64];
  __shared__ float ms[4][64];
  int ln = threadIdx.x>>6, o = threadIdx.x&63;
  int n = blockIdx.x*4+ln;
  bool ok = (n<N);
  float h = ok ? outOld[(size_t)n*64+o] : 0.f;
  hs[ln][o] = h;
  __syncthreads();
  float root = 0.f;
  #pragma unroll 8
  for (int i=0;i<64;i++) root = fmaf(hs[ln][i], rootT[i*64+o], root);
  float d = ok ? fmaxf(deg[n], 1.f) : 1.f;
  float a = ok ? agg[(size_t)n*64+o]/d : 0.f;
  float m = fmaxf(a + root + conv_b[o], 0.f);
  ms[ln][o] = m;
  __syncthreads();
  float gir=b_ih[o], giz=b_ih[64+o], gin=b_ih[128+o];
  float ghr=b_hh[o], ghz=b_hh[64+o], ghn=b_hh[128+o];
  #pragma unroll 4
  for (int i=0;i<64;i++){
    float mi = ms[ln][i], hi = hs[ln][i];
    gir = fmaf(mi, wihT[i*192+o],      gir);
    giz = fmaf(mi, wihT[i*192+64+o],   giz);
    gin = fmaf(mi, wihT[i*192+128+o],  gin);
    ghr = fmaf(hi, whhT[i*192+o],      ghr);
    ghz = fmaf(hi, whhT[i*192+64+o],   ghz);
    ghn = fmaf(hi, whhT[i*192+128+o],  ghn);
  }
  float r = sigmoidf_(gir+ghr);
  float z = sigmoidf_(giz+ghz);
  float nn = tanhf(gin + r*ghn);
  if (ok) outNew[(size_t)n*64+o] = (1.f-z)*nn + z*h;
}

// ---------------- Set2Set (3 steps) + final MLP: one block per graph ----------------
__global__ __launch_bounds__(256) void k_set2set(const float* __restrict__ out,
    const int* __restrict__ batch, int N,
    const float* __restrict__ lwihT, const float* __restrict__ lwhhT,
    const float* __restrict__ b_ih, const float* __restrict__ b_hh,
    const float* __restrict__ lin1T, const float* __restrict__ lin1_b,
    const float* __restrict__ lin2_w, const float* __restrict__ lin2_b,
    float* __restrict__ y)
{
  __shared__ float qstar[128], hl[64], cl[64], g[256];
  __shared__ float rpart[4][64], spart[4], redm[4], zs[64];
  __shared__ int sb[2];
  const int tid = threadIdx.x;
  const int b = blockIdx.x;
  const int wid = tid>>6, lane = tid&63;
  if (tid < 128) qstar[tid] = 0.f;
  if (tid < 64){ hl[tid]=0.f; cl[tid]=0.f; }
  if (tid == 0){
    int lo=0, hi=N;
    while (lo<hi){ int mid=(lo+hi)>>1; if (batch[mid] < b) lo=mid+1; else hi=mid; }
    sb[0]=lo;
    int lo2=lo, hi2=N;
    while (lo2<hi2){ int mid=(lo2+hi2)>>1; if (batch[mid] < b+1) lo2=mid+1; else hi2=mid; }
    sb[1]=lo2;
  }
  __syncthreads();
  const int nlo = sb[0], nhi = sb[1];
  for (int step=0; step<3; step++){
    float gs = b_ih[tid] + b_hh[tid];
    for (int j=0;j<128;j++) gs = fmaf(qstar[j], lwihT[j*256+tid], gs);
    for (int j=0;j<64;j++)  gs = fmaf(hl[j],    lwhhT[j*256+tid], gs);
    g[tid] = gs;
    __syncthreads();
    if (tid < 64){
      float ig = sigmoidf_(g[tid]);
      float fg = sigmoidf_(g[64+tid]);
      float gg = tanhf(g[128+tid]);
      float og = sigmoidf_(g[192+tid]);
      float c = fg*cl[tid] + ig*gg;
      cl[tid] = c;
      hl[tid] = og*tanhf(c);
    }
    __syncthreads();
    float qv = hl[lane];
    float lm = -INFINITY;
    for (int n = nlo + wid; n < nhi; n += 4){
      float p = out[(size_t)n*64 + lane]*qv;
      p += __shfl_xor(p,1); p += __shfl_xor(p,2); p += __shfl_xor(p,4);
      p += __shfl_xor(p,8); p += __shfl_xor(p,16); p += __shfl_xor(p,32);
      lm = fmaxf(lm, p);
    }
    if (lane==0) redm[wid] = lm;
    __syncthreads();
    if (tid==0) redm[0] = fmaxf(fmaxf(redm[0],redm[1]), fmaxf(redm[2],redm[3]));
    __syncthreads();
    float gmax = redm[0];
    float sw = 0.f, racc = 0.f;
    for (int n = nlo + wid; n < nhi; n += 4){
      float ol = out[(size_t)n*64 + lane];
      float p = ol*qv;
      p += __shfl_xor(p,1); p += __shfl_xor(p,2); p += __shfl_xor(p,4);
      p += __shfl_xor(p,8); p += __shfl_xor(p,16); p += __shfl_xor(p,32);
      float a = expf(p - gmax);
      sw += a;
      racc = fmaf(a, ol, racc);
    }
    rpart[wid][lane] = racc;
    if (lane==0) spart[wid] = sw;
    __syncthreads();
    if (tid < 64){
      float r = rpart[0][tid]+rpart[1][tid]+rpart[2][tid]+rpart[3][tid];
      float s = spart[0]+spart[1]+spart[2]+spart[3];
      qstar[tid] = hl[tid];
      qstar[64+tid] = (nhi>nlo) ? r/s : 0.f;
    }
    __syncthreads();
  }
  if (tid < 64){
    float acc = lin1_b[tid];
    for (int j=0;j<128;j++) acc = fmaf(qstar[j], lin1T[j*64+tid], acc);
    zs[tid] = fmaxf(acc, 0.f);
  }
  __syncthreads();
  if (tid < 64){
    float v = zs[lane]*lin2_w[lane];
    v += __shfl_xor(v,1); v += __shfl_xor(v,2); v += __shfl_xor(v,4);
    v += __shfl_xor(v,8); v += __shfl_xor(v,16); v += __shfl_xor(v,32);
    if (lane==0) y[b] = v + lin2_b[0];
  }
}

extern "C" void kernel_launch(void* const* d_in, const int* in_sizes, int n_in,
                              void* d_out, int out_size, void* d_ws, size_t ws_size,
                              hipStream_t stream)
{
  const float* x      = (const float*)d_in[0];
  const float* eattr  = (const float*)d_in[1];
  const float* lin0_w = (const float*)d_in[2];
  const float* lin0_b = (const float*)d_in[3];
  const float* nn1_w  = (const float*)d_in[4];
  const float* nn1_b  = (const float*)d_in[5];
  const float* nn2_w  = (const float*)d_in[6];
  const float* nn2_b  = (const float*)d_in[7];
  const float* root_w = (const float*)d_in[8];
  const float* conv_b = (const float*)d_in[9];
  const float* gwih   = (const float*)d_in[10];
  const float* gwhh   = (const float*)d_in[11];
  const float* gbih   = (const float*)d_in[12];
  const float* gbhh   = (const float*)d_in[13];
  const float* lwih   = (const float*)d_in[14];
  const float* lwhh   = (const float*)d_in[15];
  const float* lbih   = (const float*)d_in[16];
  const float* lbhh   = (const float*)d_in[17];
  const float* lin1_w = (const float*)d_in[18];
  const float* lin1_b = (const float*)d_in[19];
  const float* lin2_w = (const float*)d_in[20];
  const float* lin2_b = (const float*)d_in[21];
  const int*   eidx   = (const int*)d_in[22];
  const int*   batch  = (const int*)d_in[23];

  const int N = in_sizes[0]/FN;
  const int E = in_sizes[1]/FE;
  const int* srcI = eidx;
  const int* dstI = eidx + E;

  char* w = (char*)d_ws;
  size_t off = 0;
  auto alloc = [&](size_t bytes)->char* {
    char* p = w + off;
    off = (off + bytes + 255) & ~(size_t)255;
    return p;
  };
  float* degw  = (float*)alloc((size_t)N*4);
  int*   scnt  = (int*)alloc((size_t)N*4);
  int*   starts= (int*)alloc((size_t)(N+1)*4);
  int*   cursor= (int*)alloc((size_t)N*4);
  int*   bsum  = (int*)alloc((size_t)256*4);
  int*   sortedE=(int*)alloc((size_t)E*4);
  float* outA  = (float*)alloc((size_t)N*64*4);
  float* outB  = (float*)alloc((size_t)N*64*4);
  float* agg   = (float*)alloc((size_t)N*64*4);
  float* bterm = (float*)alloc((size_t)N*64*4);
  float* hidden= (float*)alloc((size_t)E*128*4);
  float* msg   = (float*)alloc((size_t)E*64*4);
  float* B2    = (float*)alloc((size_t)524288*4);
  float* lin0T = (float*)alloc((size_t)92*64*4);
  float* nn1T  = (float*)alloc((size_t)41*128*4);
  float* rootT = (float*)alloc((size_t)64*64*4);
  float* wihT  = (float*)alloc((size_t)64*192*4);
  float* whhT  = (float*)alloc((size_t)64*192*4);
  float* lwihT = (float*)alloc((size_t)128*256*4);
  float* lwhhT = (float*)alloc((size_t)64*256*4);
  float* lin1T = (float*)alloc((size_t)128*64*4);
  float* Q     = (float*)alloc((size_t)N*4096*4);   // one h-chunk: [n][h*64+o]

  const int NB = (N+255)/256;   // scan blocks (<=256)

  hipMemsetAsync(degw, 0, (size_t)N*4, stream);
  hipMemsetAsync(scnt, 0, (size_t)N*4, stream);
  k_pack<<<(97152+255)/256, 256, 0, stream>>>(lin0_w, nn1_w, root_w, gwih, gwhh,
      lwih, lwhh, lin1_w, lin0T, nn1T, rootT, wihT, whhT, lwihT, lwhhT, lin1T);
  k_pack_b2<<<524288/256, 256, 0, stream>>>(nn2_w, B2);
  k_node_mlp<<<(N+3)/4, 256, 0, stream>>>(x, lin0T, lin0_b, outA, N);
  k_edge_mlp<<<(E+1)/2, 256, 0, stream>>>(eattr, nn1T, nn1_b, hidden, E);
  k_count<<<(E+255)/256, 256, 0, stream>>>(dstI, srcI, degw, scnt, E);
  k_scan1<<<NB, 256, 0, stream>>>(scnt, starts, bsum, N);
  k_scan2<<<1, 256, 0, stream>>>(bsum, NB);
  k_scan3<<<NB, 256, 0, stream>>>(starts, cursor, bsum, N, E);
  k_sort<<<(E+255)/256, 256, 0, stream>>>(srcI, cursor, sortedE, E);

  float* cur = outA; float* nxt = outB;
  const int gemmGy = (N+63)/64;
  const int gatherGx = (E+3)/4;
  for (int conv=0; conv<2; conv++){
    k_bterm<<<(N+3)/4, 256, 0, stream>>>(cur, nn2_b, bterm, N);
    hipMemsetAsync(agg, 0, (size_t)N*64*4, stream);
    // chunk 0 (h in [0,64))
    k_qgemm<<<dim3(64, gemmGy), 256, 0, stream>>>(cur, B2, Q, N);
    k_edge_gather<0><<<gatherGx, 256, 0, stream>>>(Q, hidden, 0, bterm, srcI, dstI, sortedE, msg, agg, E);
    // chunk 1 (h in [64,128))
    k_qgemm<<<dim3(64, gemmGy), 256, 0, stream>>>(cur, B2 + 262144, Q, N);
    k_edge_gather<1><<<gatherGx, 256, 0, stream>>>(Q, hidden, 64, bterm, srcI, dstI, sortedE, msg, agg, E);
    k_node_update<<<(N+3)/4, 256, 0, stream>>>(cur, agg, degw, rootT, conv_b,
        wihT, whhT, gbih, gbhh, nxt, N);
    float* t = cur; cur = nxt; nxt = t;
  }

  k_set2set<<<128, 256, 0, stream>>>(cur, batch, N, lwihT, lwhhT, lbih, lbhh,
      lin1T, lin1_b, lin2_w, lin2_b, (float*)d_out);
}